// Round 1
// baseline (2334.260 us; speedup 1.0000x reference)
//
#include <hip/hip_runtime.h>

#define DD 256
#define NN 32768
#define KK 8192
#define TN 64   // tokens per block
#define TK 64   // codes per k-tile

// ---------------------------------------------------------------------------
// Kernel 1: e_sq[k] = sum_d e[k][d]^2.  One wave per codebook row.
// ---------------------------------------------------------------------------
__global__ __launch_bounds__(256) void esq_kernel(const float* __restrict__ e,
                                                  float* __restrict__ esq) {
    const int wave = threadIdx.x >> 6;
    const int lane = threadIdx.x & 63;
    const int k = blockIdx.x * 4 + wave;
    const float4* row = (const float4*)(e + (size_t)k * DD);
    float4 v = row[lane];                       // 64 lanes * 16B = 256 floats
    float s = v.x * v.x + v.y * v.y + v.z * v.z + v.w * v.w;
    #pragma unroll
    for (int off = 32; off > 0; off >>= 1) s += __shfl_down(s, off, 64);
    if (lane == 0) esq[k] = s;
}

// ---------------------------------------------------------------------------
// Kernel 2: per block of 64 tokens, scan all 8192 codes.
//   score(k, n) = e_sq[k] - 2 * dot(z[:, n], e[k, :])   (z_sq is argmin-invariant)
// Thread (tx=tid&15, ty=tid>>4) owns tokens {tx+16i} and codes {k0+ty+16j}.
// Full z-tile lives in LDS [d][n] (64 KB). Embeddings stream from global
// (L2/L3-resident) as float4.
// ---------------------------------------------------------------------------
__global__ __launch_bounds__(256) void vq_kernel(const float* __restrict__ z,
                                                 const float* __restrict__ e,
                                                 const float* __restrict__ esq,
                                                 float* __restrict__ out) {
    __shared__ float zs[DD][TN];   // 65536 B exactly

    const int tid = threadIdx.x;
    const int tx = tid & 15;
    const int ty = tid >> 4;
    const int n0 = blockIdx.x * TN;

    // Stage z tile once: zs[d][c] = z[d*NN + n0 + c]  (coalesced: c consecutive)
    {
        const int c = tid & 63;
        const int d0 = tid >> 6;
        #pragma unroll 4
        for (int d = d0; d < DD; d += 4)
            zs[d][c] = z[(size_t)d * NN + n0 + c];
    }
    __syncthreads();

    float bestv[4] = {3.4e38f, 3.4e38f, 3.4e38f, 3.4e38f};
    int   besti[4] = {0, 0, 0, 0};

    for (int k0 = 0; k0 < KK; k0 += TK) {
        const float4* er[4];
        float eq[4];
        #pragma unroll
        for (int j = 0; j < 4; ++j) {
            const int k = k0 + ty + 16 * j;
            er[j] = (const float4*)(e + (size_t)k * DD);
            eq[j] = esq[k];
        }

        float acc[4][4];
        #pragma unroll
        for (int i = 0; i < 4; ++i)
            #pragma unroll
            for (int j = 0; j < 4; ++j) acc[i][j] = 0.0f;

        #pragma unroll 4
        for (int d4 = 0; d4 < DD / 4; ++d4) {
            float4 ev[4];
            #pragma unroll
            for (int j = 0; j < 4; ++j) ev[j] = er[j][d4];
            #pragma unroll
            for (int dd = 0; dd < 4; ++dd) {
                float zv[4];
                #pragma unroll
                for (int i = 0; i < 4; ++i) zv[i] = zs[d4 * 4 + dd][tx + 16 * i];
                #pragma unroll
                for (int i = 0; i < 4; ++i) {
                    #pragma unroll
                    for (int j = 0; j < 4; ++j)
                        acc[i][j] += zv[i] * ((const float*)&ev[j])[dd];
                }
            }
        }

        // score + running min (k increasing within thread -> strict < keeps
        // the earliest index, matching argmin first-occurrence)
        #pragma unroll
        for (int j = 0; j < 4; ++j) {
            const int k = k0 + ty + 16 * j;
            #pragma unroll
            for (int i = 0; i < 4; ++i) {
                const float s = eq[j] - 2.0f * acc[i][j];
                if (s < bestv[i]) { bestv[i] = s; besti[i] = k; }
            }
        }
    }

    // ---- cross-thread reduction over ty (16 partials per token) ----
    __syncthreads();                       // all threads done reading zs
    float* lds  = &zs[0][0];
    float* vred = lds;                     // [16][64]
    int*   ired = (int*)lds + 1024;        // [16][64]
    int*   fin  = (int*)lds + 2048;        // [64]

    #pragma unroll
    for (int i = 0; i < 4; ++i) {
        const int l = tx + 16 * i;
        vred[ty * 64 + l] = bestv[i];
        ired[ty * 64 + l] = besti[i];
    }
    __syncthreads();

    if (tid < 64) {
        float bv = vred[tid];
        int   bi = ired[tid];
        #pragma unroll
        for (int t = 1; t < 16; ++t) {
            const float v  = vred[t * 64 + tid];
            const int   ix = ired[t * 64 + tid];
            if (v < bv || (v == bv && ix < bi)) { bv = v; bi = ix; }
        }
        fin[tid] = bi;
        // indices output (as float values; exact for idx < 2^24)
        out[(size_t)DD * NN + n0 + tid] = (float)bi;
    }
    __syncthreads();

    // ---- gather z_q[:, n] = e[idx[n], :] ; coalesced stores over n ----
    {
        const int l  = tid & 63;
        const int d0 = tid >> 6;
        const int kk = fin[l];
        const float* row = e + (size_t)kk * DD;
        #pragma unroll 4
        for (int d = d0; d < DD; d += 4)
            out[(size_t)d * NN + n0 + l] = row[d];
    }
}

extern "C" void kernel_launch(void* const* d_in, const int* in_sizes, int n_in,
                              void* d_out, int out_size, void* d_ws, size_t ws_size,
                              hipStream_t stream) {
    const float* z   = (const float*)d_in[0];   // (D, N) fp32
    const float* e   = (const float*)d_in[1];   // (K, D) fp32
    float*       out = (float*)d_out;           // z_q (D*N) then indices (N)
    float*       esq = (float*)d_ws;            // K floats scratch

    esq_kernel<<<KK / 4, 256, 0, stream>>>(e, esq);
    vq_kernel<<<NN / TN, 256, 0, stream>>>(z, e, esq, out);
}

// Round 2
// 1088.026 us; speedup vs baseline: 2.1454x; 2.1454x over previous
//
#include <hip/hip_runtime.h>

#define D_DIM 256
#define N_TOK 32768
#define K_CB  8192
#define TAU   0.125f

typedef float  f32x16 __attribute__((ext_vector_type(16)));
typedef float  f32x4  __attribute__((ext_vector_type(4)));
typedef short  s16x8  __attribute__((ext_vector_type(8)));

// ---- workspace layout (bytes) ----
#define OFF_ESQ   0                        // 8192 f32
#define OFF_CNT   32768                    // int (+pad)
#define OFF_MARG  33024                    // 32768 f32
#define OFF_LIST  164096                   // 32768 i32
#define OFF_FIXB  295168                   // 32768 u64
#define OFF_Z2H   557312                   // 32*32768*8 bf16 = 16 MB
#define OFF_Z2L   (OFF_Z2H + 16777216)
#define OFF_EHT   (OFF_Z2L + 16777216)     // 32*8192*8 bf16 = 4 MB
#define OFF_ELT   (OFF_EHT + 4194304)
#define WS_NEED   ((size_t)(OFF_ELT + 4194304))

#define SMEM_BYTES 135168

#define GLOAD_LDS16(g, s) \
  __builtin_amdgcn_global_load_lds((const __attribute__((address_space(1))) unsigned int*)(g), \
                                   (__attribute__((address_space(3))) unsigned int*)(s), 16, 0, 0)

static __device__ __forceinline__ short f32_to_bf16(float f) {
  unsigned u = __float_as_uint(f);
  unsigned r = (u + 0x7FFFu + ((u >> 16) & 1u)) >> 16;   // RNE
  return (short)r;
}
static __device__ __forceinline__ float bf16_to_f32(short s) {
  return __uint_as_float(((unsigned)(unsigned short)s) << 16);
}

// ===========================================================================
// P1: z2h/z2l[c][n][8] = bf16 hi/lo split of -2*z[d][n], d = 8c+j (tiled+transposed)
// ===========================================================================
__global__ __launch_bounds__(256) void zprep_kernel(const float* __restrict__ z,
                                                    short* __restrict__ z2h,
                                                    short* __restrict__ z2l) {
  const int n = blockIdx.x * 256 + threadIdx.x;
  for (int c = 0; c < 32; ++c) {
    s16x8 hv, lv;
    #pragma unroll
    for (int i = 0; i < 8; ++i) {
      float x = -2.0f * z[(size_t)(c * 8 + i) * N_TOK + n];   // coalesced over n
      short h = f32_to_bf16(x);
      short l = f32_to_bf16(x - bf16_to_f32(h));
      hv[i] = h; lv[i] = l;
    }
    *(s16x8*)(z2h + ((size_t)c * N_TOK + n) * 8) = hv;        // 16B/thread, coalesced
    *(s16x8*)(z2l + ((size_t)c * N_TOK + n) * 8) = lv;
  }
}

// ===========================================================================
// P2: eht/elt[c][k][8] = bf16 hi/lo split of e[k][8c+j]; esq[k]; zero counter
// ===========================================================================
__global__ __launch_bounds__(256) void eprep_kernel(const float* __restrict__ e,
                                                    short* __restrict__ eht,
                                                    short* __restrict__ elt,
                                                    float* __restrict__ esq,
                                                    int* __restrict__ cnt) {
  if (blockIdx.x == 0 && threadIdx.x == 0) *cnt = 0;
  const int tid = threadIdx.x;
  const int c = tid & 31, kk = tid >> 5;
  const int k = blockIdx.x * 8 + kk;
  float v[8]; float ss = 0.f;
  #pragma unroll
  for (int i = 0; i < 8; ++i) {
    v[i] = e[(size_t)k * D_DIM + c * 8 + i];
    ss += v[i] * v[i];
  }
  #pragma unroll
  for (int m = 1; m < 32; m <<= 1) ss += __shfl_xor(ss, m, 64);  // 32-lane group sum
  if (c == 0) esq[k] = ss;
  s16x8 hv, lv;
  #pragma unroll
  for (int i = 0; i < 8; ++i) {
    short h = f32_to_bf16(v[i]);
    short l = f32_to_bf16(v[i] - bf16_to_f32(h));
    hv[i] = h; lv[i] = l;
  }
  *(s16x8*)(eht + ((size_t)c * K_CB + k) * 8) = hv;
  *(s16x8*)(elt + ((size_t)c * K_CB + k) * 8) = lv;
}

// ===========================================================================
// Main: 512 blocks x 512 thr (8 waves). 64 tokens/block resident in LDS (hi/lo),
// codes streamed 1024/chunk, 16-d groups. Wave = 128 codes x 64 tokens
// (4x2 frags of 32x32x16 bf16). score = esq[k] + sum (-2z)*e via 3 MFMAs.
// Tracks best+second per token for margin verification.
// ===========================================================================
__global__ __launch_bounds__(512, 2) void vq_mfma_kernel(
    const float* __restrict__ e, const float* __restrict__ ws_esq,
    const short* __restrict__ z2h, const short* __restrict__ z2l,
    const short* __restrict__ eht, const short* __restrict__ elt,
    float* __restrict__ out, float* __restrict__ marg) {
  extern __shared__ char smem[];
  short* zs_h = (short*)(smem);                 // [32][64][8] = 32 KB
  short* zs_l = (short*)(smem + 32768);
  short* es_h = (short*)(smem + 65536);         // [2][1024][8] = 32 KB
  short* es_l = (short*)(smem + 98304);
  float* eq   = (float*)(smem + 131072);        // [1024] f32

  const int tid  = threadIdx.x;
  const int w    = tid >> 6;          // wave 0..7
  const int lane = tid & 63;
  const int half = lane >> 5;
  const int l31  = lane & 31;
  const int n0   = blockIdx.x * 64;
  const int wc0  = w * 128;           // wave's code base within 1024-chunk

  // ---- stage z tile once: 64 wave-instrs (8/wave), 16B/lane contiguous ----
  #pragma unroll
  for (int i = 0; i < 8; ++i) {
    int q = w * 8 + i;                // 0..63
    int hl = q >> 5;                  // 0=hi 1=lo
    int c  = q & 31;
    const short* src = (hl ? z2l : z2h) + ((size_t)c * N_TOK + n0) * 8 + lane * 8;
    short* dst = (hl ? zs_l : zs_h) + c * 64 * 8;
    GLOAD_LDS16(src, dst);
  }

  float bestv[2] = {3.4e38f, 3.4e38f};
  float secv[2]  = {3.4e38f, 3.4e38f};
  int   bestk[2] = {0, 0};

  for (int cc = 0; cc < 8; ++cc) {
    f32x16 acc[4][2];
    #pragma unroll
    for (int f = 0; f < 4; ++f)
      #pragma unroll
      for (int j = 0; j < 2; ++j)
        #pragma unroll
        for (int r = 0; r < 16; ++r) acc[f][j][r] = 0.f;

    for (int dc = 0; dc < 16; ++dc) {          // 16 d per iter (2 chunks of 8)
      __syncthreads();                         // protect es reuse
      #pragma unroll
      for (int i = 0; i < 8; ++i) {
        int q = w * 8 + i;
        int p = q >> 4;                        // 0:h-c0 1:h-c1 2:l-c0 3:l-c1
        int seg = q & 15;
        int cg = 2 * dc + (p & 1);
        const short* src = (p < 2 ? eht : elt) +
            ((size_t)cg * K_CB + cc * 1024 + seg * 64) * 8 + lane * 8;
        short* dst = (p < 2 ? es_h : es_l) + ((p & 1) * 1024 + seg * 64) * 8;
        GLOAD_LDS16(src, dst);
      }
      if (dc == 0 && w < 4) {                  // stage eq (4 KB) once per chunk
        const float* src = ws_esq + cc * 1024 + w * 256 + lane * 4;
        float* dst = eq + w * 256;
        GLOAD_LDS16(src, dst);
      }
      __syncthreads();

      s16x8 ah[4], al[4], bh[2], bl[2];
      #pragma unroll
      for (int j = 0; j < 2; ++j) {
        int zoff = ((2 * dc + half) * 64 + 32 * j + l31) * 8;
        bh[j] = *(const s16x8*)(zs_h + zoff);
        bl[j] = *(const s16x8*)(zs_l + zoff);
      }
      #pragma unroll
      for (int f = 0; f < 4; ++f) {
        int eoff = (half * 1024 + wc0 + 32 * f + l31) * 8;
        ah[f] = *(const s16x8*)(es_h + eoff);
        al[f] = *(const s16x8*)(es_l + eoff);
      }
      #pragma unroll
      for (int f = 0; f < 4; ++f)
        #pragma unroll
        for (int j = 0; j < 2; ++j) {
          acc[f][j] = __builtin_amdgcn_mfma_f32_32x32x16_bf16(ah[f], bh[j], acc[f][j], 0, 0, 0);
          acc[f][j] = __builtin_amdgcn_mfma_f32_32x32x16_bf16(ah[f], bl[j], acc[f][j], 0, 0, 0);
          acc[f][j] = __builtin_amdgcn_mfma_f32_32x32x16_bf16(al[f], bh[j], acc[f][j], 0, 0, 0);
        }
    }

    // epilogue: score = acc + esq; running best/second (k strictly ascending)
    #pragma unroll
    for (int f = 0; f < 4; ++f) {
      int cbase = wc0 + 32 * f + 4 * half;
      #pragma unroll
      for (int g = 0; g < 4; ++g) {
        f32x4 eqv = *(const f32x4*)(eq + cbase + 8 * g);
        #pragma unroll
        for (int r = 0; r < 4; ++r) {
          int reg = g * 4 + r;
          int kglob = cc * 1024 + cbase + 8 * g + r;
          #pragma unroll
          for (int j = 0; j < 2; ++j) {
            float s = acc[f][j][reg] + eqv[r];
            if (s < bestv[j]) { secv[j] = bestv[j]; bestv[j] = s; bestk[j] = kglob; }
            else if (s < secv[j]) secv[j] = s;
          }
        }
      }
    }
  }

  // ---- cross-wave merge: 16 partials per token ----
  __syncthreads();
  float* pv  = (float*)(smem + 65536);            // [16][64]
  int*   pk  = (int*)  (smem + 65536 + 4096);
  float* ps  = (float*)(smem + 65536 + 8192);
  int*   fin = (int*)  (smem + 65536 + 12288);
  int slot = w * 2 + half;
  #pragma unroll
  for (int j = 0; j < 2; ++j) {
    int t = 32 * j + l31;
    pv[slot * 64 + t] = bestv[j];
    pk[slot * 64 + t] = bestk[j];
    ps[slot * 64 + t] = secv[j];
  }
  __syncthreads();
  if (tid < 64) {
    float bv = pv[tid]; int bk = pk[tid]; float sc = ps[tid];
    for (int t = 1; t < 16; ++t) {
      float v = pv[t * 64 + tid]; int k2 = pk[t * 64 + tid]; float s2 = ps[t * 64 + tid];
      if (v < bv || (v == bv && k2 < bk)) { sc = fminf(bv, s2); bv = v; bk = k2; }
      else                                { sc = fminf(sc, v); }
    }
    fin[tid] = bk;
    out[(size_t)D_DIM * N_TOK + n0 + tid] = (float)bk;   // indices as float
    marg[n0 + tid] = sc - bv;
  }
  __syncthreads();
  // ---- z_q gather (approx index; pass B fixes flagged tokens) ----
  {
    int t = tid & 63, d0 = tid >> 6;     // d0 0..7
    int kk = fin[t];
    const float* row = e + (size_t)kk * D_DIM;
    #pragma unroll 4
    for (int dd = 0; dd < 32; ++dd) {
      int d = d0 * 32 + dd;
      out[(size_t)d * N_TOK + n0 + t] = row[d];   // coalesced over t
    }
  }
}

// ===========================================================================
// C1: compact flagged tokens (margin < TAU), init their fix slots
// ===========================================================================
__global__ __launch_bounds__(256) void flag_kernel(const float* __restrict__ marg,
                                                   int* __restrict__ cnt,
                                                   int* __restrict__ list,
                                                   unsigned long long* __restrict__ fixb) {
  int n = blockIdx.x * 256 + threadIdx.x;
  if (marg[n] < TAU) {
    int p = atomicAdd(cnt, 1);
    list[p] = n;
    fixb[n] = 0xFFFFFFFFFFFFFFFFULL;
  }
}

// ===========================================================================
// C2: exact fp32 rescan of flagged tokens, 1024-code slabs, packed atomicMin
// ===========================================================================
__global__ __launch_bounds__(256) void rescan_kernel(
    const float* __restrict__ z, const float* __restrict__ e,
    const float* __restrict__ esq, const int* __restrict__ cnt,
    const int* __restrict__ list, unsigned long long* __restrict__ fixb) {
  __shared__ float zs[256];
  __shared__ unsigned long long red[256];
  const int tid = threadIdx.x;
  const int items = (*(volatile const int*)cnt) * 8;
  for (int it = blockIdx.x; it < items; it += gridDim.x) {
    int n = list[it >> 3];
    int slab = (it & 7) * 1024;
    __syncthreads();
    zs[tid] = z[(size_t)tid * N_TOK + n];
    __syncthreads();
    unsigned long long lmin = 0xFFFFFFFFFFFFFFFFULL;
    for (int q = 0; q < 4; ++q) {
      int k = slab + q * 256 + tid;
      const f32x4* row = (const f32x4*)(e + (size_t)k * D_DIM);
      float dot = 0.f;
      #pragma unroll 8
      for (int d4 = 0; d4 < 64; ++d4) {
        f32x4 ev = row[d4];
        dot += zs[d4*4+0]*ev[0] + zs[d4*4+1]*ev[1] + zs[d4*4+2]*ev[2] + zs[d4*4+3]*ev[3];
      }
      float s = esq[k] - 2.0f * dot + 1024.0f;          // bias > 0 for packing
      unsigned long long p = ((unsigned long long)__float_as_uint(s) << 32) | (unsigned)k;
      lmin = (p < lmin) ? p : lmin;
    }
    red[tid] = lmin; __syncthreads();
    for (int off = 128; off > 0; off >>= 1) {
      if (tid < off && red[tid + off] < red[tid]) red[tid] = red[tid + off];
      __syncthreads();
    }
    if (tid == 0) atomicMin(&fixb[n], red[0]);
  }
}

// ===========================================================================
// C3: write exact idx + z_q column for flagged tokens
// ===========================================================================
__global__ __launch_bounds__(256) void fixup_kernel(const float* __restrict__ marg,
                                                    const unsigned long long* __restrict__ fixb,
                                                    const float* __restrict__ e,
                                                    float* __restrict__ out) {
  __shared__ int fk[64];
  const int tid = threadIdx.x;
  const int n0 = blockIdx.x * 64;
  if (tid < 64) {
    int n = n0 + tid;
    int k = -1;
    if (marg[n] < TAU) {
      k = (int)(unsigned)(fixb[n] & 0xFFFFFFFFu);
      out[(size_t)D_DIM * N_TOK + n] = (float)k;
    }
    fk[tid] = k;
  }
  __syncthreads();
  int t = tid & 63, d0 = tid >> 6;                // d0 0..3
  int k = fk[t];
  if (k >= 0) {
    const float* row = e + (size_t)k * D_DIM;
    for (int dd = 0; dd < 64; ++dd) {
      int d = d0 * 64 + dd;
      out[(size_t)d * N_TOK + n0 + t] = row[d];
    }
  }
}

// ======================= fallback (round-1 fp32 path) =======================
__global__ __launch_bounds__(256) void esq_kernel(const float* __restrict__ e,
                                                  float* __restrict__ esq) {
  const int wave = threadIdx.x >> 6, lane = threadIdx.x & 63;
  const int k = blockIdx.x * 4 + wave;
  const float4* row = (const float4*)(e + (size_t)k * D_DIM);
  float4 v = row[lane];
  float s = v.x*v.x + v.y*v.y + v.z*v.z + v.w*v.w;
  #pragma unroll
  for (int off = 32; off > 0; off >>= 1) s += __shfl_down(s, off, 64);
  if (lane == 0) esq[k] = s;
}

__global__ __launch_bounds__(256) void vq_kernel(const float* __restrict__ z,
                                                 const float* __restrict__ e,
                                                 const float* __restrict__ esq,
                                                 float* __restrict__ out) {
  __shared__ float zs[D_DIM][64];
  const int tid = threadIdx.x, tx = tid & 15, ty = tid >> 4;
  const int n0 = blockIdx.x * 64;
  {
    const int c = tid & 63, d0 = tid >> 6;
    #pragma unroll 4
    for (int d = d0; d < D_DIM; d += 4) zs[d][c] = z[(size_t)d * N_TOK + n0 + c];
  }
  __syncthreads();
  float bestv[4] = {3.4e38f,3.4e38f,3.4e38f,3.4e38f};
  int   besti[4] = {0,0,0,0};
  for (int k0 = 0; k0 < K_CB; k0 += 64) {
    const float4* er[4]; float eqv[4];
    #pragma unroll
    for (int j = 0; j < 4; ++j) {
      int k = k0 + ty + 16 * j;
      er[j] = (const float4*)(e + (size_t)k * D_DIM);
      eqv[j] = esq[k];
    }
    float acc[4][4];
    #pragma unroll
    for (int i = 0; i < 4; ++i)
      #pragma unroll
      for (int j = 0; j < 4; ++j) acc[i][j] = 0.f;
    #pragma unroll 4
    for (int d4 = 0; d4 < D_DIM/4; ++d4) {
      float4 ev[4];
      #pragma unroll
      for (int j = 0; j < 4; ++j) ev[j] = er[j][d4];
      #pragma unroll
      for (int dd = 0; dd < 4; ++dd) {
        float zv[4];
        #pragma unroll
        for (int i = 0; i < 4; ++i) zv[i] = zs[d4*4+dd][tx + 16*i];
        #pragma unroll
        for (int i = 0; i < 4; ++i)
          #pragma unroll
          for (int j = 0; j < 4; ++j) acc[i][j] += zv[i] * ((const float*)&ev[j])[dd];
      }
    }
    #pragma unroll
    for (int j = 0; j < 4; ++j) {
      int k = k0 + ty + 16 * j;
      #pragma unroll
      for (int i = 0; i < 4; ++i) {
        float s = eqv[j] - 2.0f * acc[i][j];
        if (s < bestv[i]) { bestv[i] = s; besti[i] = k; }
      }
    }
  }
  __syncthreads();
  float* lds = &zs[0][0];
  float* vred = lds; int* ired = (int*)lds + 1024; int* fin = (int*)lds + 2048;
  #pragma unroll
  for (int i = 0; i < 4; ++i) {
    int l = tx + 16 * i;
    vred[ty * 64 + l] = bestv[i]; ired[ty * 64 + l] = besti[i];
  }
  __syncthreads();
  if (tid < 64) {
    float bv = vred[tid]; int bi = ired[tid];
    #pragma unroll
    for (int t = 1; t < 16; ++t) {
      float v = vred[t*64+tid]; int ix = ired[t*64+tid];
      if (v < bv || (v == bv && ix < bi)) { bv = v; bi = ix; }
    }
    fin[tid] = bi;
    out[(size_t)D_DIM * N_TOK + n0 + tid] = (float)bi;
  }
  __syncthreads();
  {
    const int l = tid & 63, d0 = tid >> 6;
    const int kk = fin[l];
    const float* row = e + (size_t)kk * D_DIM;
    #pragma unroll 4
    for (int d = d0; d < D_DIM; d += 4) out[(size_t)d * N_TOK + n0 + l] = row[d];
  }
}

extern "C" void kernel_launch(void* const* d_in, const int* in_sizes, int n_in,
                              void* d_out, int out_size, void* d_ws, size_t ws_size,
                              hipStream_t stream) {
  const float* z = (const float*)d_in[0];
  const float* e = (const float*)d_in[1];
  float* out = (float*)d_out;
  char* ws = (char*)d_ws;

  if (ws_size >= WS_NEED) {
    float* esq = (float*)(ws + OFF_ESQ);
    int* cnt = (int*)(ws + OFF_CNT);
    float* marg = (float*)(ws + OFF_MARG);
    int* list = (int*)(ws + OFF_LIST);
    unsigned long long* fixb = (unsigned long long*)(ws + OFF_FIXB);
    short* z2h = (short*)(ws + OFF_Z2H);
    short* z2l = (short*)(ws + OFF_Z2L);
    short* eht = (short*)(ws + OFF_EHT);
    short* elt = (short*)(ws + OFF_ELT);

    (void)hipFuncSetAttribute((const void*)vq_mfma_kernel,
                              hipFuncAttributeMaxDynamicSharedMemorySize, SMEM_BYTES);

    zprep_kernel<<<128, 256, 0, stream>>>(z, z2h, z2l);
    eprep_kernel<<<1024, 256, 0, stream>>>(e, eht, elt, esq, cnt);
    vq_mfma_kernel<<<512, 512, SMEM_BYTES, stream>>>(e, esq, z2h, z2l, eht, elt, out, marg);
    flag_kernel<<<128, 256, 0, stream>>>(marg, cnt, list, fixb);
    rescan_kernel<<<1024, 256, 0, stream>>>(z, e, esq, cnt, list, fixb);
    fixup_kernel<<<512, 256, 0, stream>>>(marg, fixb, e, out);
  } else {
    float* esq = (float*)(ws);
    esq_kernel<<<K_CB / 4, 256, 0, stream>>>(e, esq);
    vq_kernel<<<N_TOK / 64, 256, 0, stream>>>(z, e, esq, out);
  }
}

// Round 3
// 887.920 us; speedup vs baseline: 2.6289x; 1.2254x over previous
//
#include <hip/hip_runtime.h>

#define D_DIM 256
#define N_TOK 32768
#define K_CB  8192
#define TAU   0.125f

typedef float  f32x16 __attribute__((ext_vector_type(16)));
typedef float  f32x4  __attribute__((ext_vector_type(4)));
typedef short  s16x8  __attribute__((ext_vector_type(8)));

// ---- workspace layout (bytes) ----
#define OFF_ESQ   0                        // 8192 f32 (32 KB)
#define OFF_CNT   32768                    // int (+pad)
#define OFF_MARG  33024                    // 32768 f32 (128 KB)
#define OFF_LIST  164096                   // 32768 i32 (128 KB)
#define OFF_FIXB  295168                   // 32768 u64 (256 KB)
#define OFF_EHT   557312                   // 32*8192*8 bf16 = 4 MB
#define OFF_ELT   (OFF_EHT + 4194304)
#define WS_NEED   ((size_t)(OFF_ELT + 4194304))

#define SMEM_BYTES 163840                  // 64K zs_h + 64K zs_l + 32K esq

#define GLOAD_LDS16(g, s) \
  __builtin_amdgcn_global_load_lds((const __attribute__((address_space(1))) unsigned int*)(g), \
                                   (__attribute__((address_space(3))) unsigned int*)(s), 16, 0, 0)

static __device__ __forceinline__ short f32_to_bf16(float f) {
  unsigned u = __float_as_uint(f);
  unsigned r = (u + 0x7FFFu + ((u >> 16) & 1u)) >> 16;   // RNE
  return (short)r;
}
static __device__ __forceinline__ float bf16_to_f32(short s) {
  return __uint_as_float(((unsigned)(unsigned short)s) << 16);
}

// ===========================================================================
// P: eht/elt[c][k][8] = bf16 hi/lo split of e[k][8c+j]; esq[k]; zero counter
// ===========================================================================
__global__ __launch_bounds__(256) void eprep_kernel(const float* __restrict__ e,
                                                    short* __restrict__ eht,
                                                    short* __restrict__ elt,
                                                    float* __restrict__ esq,
                                                    int* __restrict__ cnt) {
  if (blockIdx.x == 0 && threadIdx.x == 0) *cnt = 0;
  const int tid = threadIdx.x;
  const int c = tid & 31, kk = tid >> 5;
  const int k = blockIdx.x * 8 + kk;
  float v[8]; float ss = 0.f;
  #pragma unroll
  for (int i = 0; i < 8; ++i) {
    v[i] = e[(size_t)k * D_DIM + c * 8 + i];
    ss += v[i] * v[i];
  }
  #pragma unroll
  for (int m = 1; m < 32; m <<= 1) ss += __shfl_xor(ss, m, 64);  // 32-lane group sum
  if (c == 0) esq[k] = ss;
  s16x8 hv, lv;
  #pragma unroll
  for (int i = 0; i < 8; ++i) {
    short h = f32_to_bf16(v[i]);
    short l = f32_to_bf16(v[i] - bf16_to_f32(h));
    hv[i] = h; lv[i] = l;
  }
  *(s16x8*)(eht + ((size_t)c * K_CB + k) * 8) = hv;
  *(s16x8*)(elt + ((size_t)c * K_CB + k) * 8) = lv;
}

// ===========================================================================
// Main: 256 blocks x 512 thr (8 waves). 128 tokens/block in LDS (hi/lo bf16,
// split in-register at block start). e-fragments stream GLOBAL->VGPR (no LDS
// staging: zero intra-block e reuse; all blocks scan k in phase -> L2/L3
// serves them). Zero barriers in the K-loop. Wave (th=w>>2, cg=w&3):
// 128 codes x 64 tokens via 4x2 frags of mfma_f32_32x32x16_bf16, 3-term
// bf16-split (hh+hl+lh). score = esq[k] + dot(-2z, e). Tracks best+second
// per token; margin<TAU tokens appended for exact fp32 rescan.
// ===========================================================================
__global__ __launch_bounds__(512, 2) void vq_main_kernel(
    const float* __restrict__ z, const float* __restrict__ e,
    const float* __restrict__ esq_g,
    const short* __restrict__ eht, const short* __restrict__ elt,
    float* __restrict__ out, float* __restrict__ marg,
    int* __restrict__ cnt, int* __restrict__ list,
    unsigned long long* __restrict__ fixb) {
  extern __shared__ char smem[];
  short* zs_h = (short*)(smem);                 // [32][128][8] = 64 KB
  short* zs_l = (short*)(smem + 65536);         // 64 KB
  float* eqs  = (float*)(smem + 131072);        // [8192] f32 = 32 KB

  const int tid  = threadIdx.x;
  const int w    = tid >> 6;
  const int lane = tid & 63;
  const int half = lane >> 5;
  const int l31  = lane & 31;
  const int th   = w >> 2;            // token half (0/1)
  const int cg   = w & 3;             // code subgroup
  const int n0   = blockIdx.x * 128;

  // ---- stage all esq once: 32 KB, 4 insts/wave ----
  #pragma unroll
  for (int i = 0; i < 4; ++i) {
    int idx = (w * 4 + i) * 256;
    GLOAD_LDS16(esq_g + idx + lane * 4, eqs + idx);
  }

  // ---- split -2*z into bf16 hi/lo directly into LDS (fused zprep) ----
  {
    const int t = tid & 127;
    const int cb = (tid >> 7) * 8;    // 0,8,16,24
    #pragma unroll
    for (int cc = 0; cc < 8; ++cc) {
      const int c = cb + cc;
      s16x8 hv, lv;
      #pragma unroll
      for (int i = 0; i < 8; ++i) {
        float x = -2.0f * z[(size_t)(c * 8 + i) * N_TOK + n0 + t];  // coalesced over t
        short h = f32_to_bf16(x);
        short l = f32_to_bf16(x - bf16_to_f32(h));
        hv[i] = h; lv[i] = l;
      }
      *(s16x8*)(zs_h + ((size_t)c * 128 + t) * 8) = hv;
      *(s16x8*)(zs_l + ((size_t)c * 128 + t) * 8) = lv;
    }
  }
  __syncthreads();   // the only barrier before the merge

  float bestv[2] = {3.4e38f, 3.4e38f};
  float secv[2]  = {3.4e38f, 3.4e38f};
  int   bestk[2] = {0, 0};

  for (int k0 = 0; k0 < K_CB; k0 += 512) {
    const int kb = k0 + cg * 128;
    f32x16 acc[4][2];
    #pragma unroll
    for (int f = 0; f < 4; ++f)
      #pragma unroll
      for (int j = 0; j < 2; ++j)
        #pragma unroll
        for (int r = 0; r < 16; ++r) acc[f][j][r] = 0.f;

    #pragma unroll 4
    for (int dc = 0; dc < 16; ++dc) {
      s16x8 ah[4], al[4], bh[2], bl[2];
      const size_t ebase = ((size_t)(2 * dc + half) * K_CB + kb + l31) * 8;
      #pragma unroll
      for (int f = 0; f < 4; ++f) {
        ah[f] = *(const s16x8*)(eht + ebase + f * 32 * 8);   // global, coalesced 16B/lane
        al[f] = *(const s16x8*)(elt + ebase + f * 32 * 8);
      }
      const int zbase = ((2 * dc + half) * 128 + th * 64 + l31) * 8;
      #pragma unroll
      for (int j = 0; j < 2; ++j) {
        bh[j] = *(const s16x8*)(zs_h + zbase + j * 32 * 8);
        bl[j] = *(const s16x8*)(zs_l + zbase + j * 32 * 8);
      }
      #pragma unroll
      for (int f = 0; f < 4; ++f)
        #pragma unroll
        for (int j = 0; j < 2; ++j) {
          acc[f][j] = __builtin_amdgcn_mfma_f32_32x32x16_bf16(ah[f], bh[j], acc[f][j], 0, 0, 0);
          acc[f][j] = __builtin_amdgcn_mfma_f32_32x32x16_bf16(ah[f], bl[j], acc[f][j], 0, 0, 0);
          acc[f][j] = __builtin_amdgcn_mfma_f32_32x32x16_bf16(al[f], bh[j], acc[f][j], 0, 0, 0);
        }
    }

    // epilogue: score = acc + esq; running best/second (k ascending per lane)
    #pragma unroll
    for (int f = 0; f < 4; ++f) {
      const int base = kb + 32 * f + 4 * half;
      #pragma unroll
      for (int g = 0; g < 4; ++g) {
        f32x4 eqv = *(const f32x4*)(eqs + base + 8 * g);    // broadcast read
        #pragma unroll
        for (int r = 0; r < 4; ++r) {
          const int reg = g * 4 + r;
          const int kglob = base + 8 * g + r;
          #pragma unroll
          for (int j = 0; j < 2; ++j) {
            float s = acc[f][j][reg] + eqv[r];
            if (s < bestv[j]) { secv[j] = bestv[j]; bestv[j] = s; bestk[j] = kglob; }
            else if (s < secv[j]) secv[j] = s;
          }
        }
      }
    }
  }

  // ---- cross-wave merge: 8 partials per token ----
  __syncthreads();
  float* pv  = (float*)(smem);                  // [8][128]
  int*   pk  = (int*)  (smem + 4096);
  float* ps  = (float*)(smem + 8192);
  int*   fin = (int*)  (smem + 12288);          // [128]
  const int slot = cg * 2 + half;
  #pragma unroll
  for (int j = 0; j < 2; ++j) {
    const int t = th * 64 + 32 * j + l31;
    pv[slot * 128 + t] = bestv[j];
    pk[slot * 128 + t] = bestk[j];
    ps[slot * 128 + t] = secv[j];
  }
  __syncthreads();
  if (tid < 128) {
    const int t = tid;
    float bv = pv[t]; int bk = pk[t]; float sc = ps[t];
    #pragma unroll
    for (int s2 = 1; s2 < 8; ++s2) {
      float v = pv[s2 * 128 + t]; int k2 = pk[s2 * 128 + t]; float s3 = ps[s2 * 128 + t];
      if (v < bv || (v == bv && k2 < bk)) { sc = fminf(bv, s3); bv = v; bk = k2; }
      else                                { sc = fminf(sc, v); }
    }
    fin[t] = bk;
    const int n = n0 + t;
    out[(size_t)D_DIM * N_TOK + n] = (float)bk;     // indices as float (exact)
    const float m = sc - bv;
    marg[n] = m;
    if (m < TAU) {                                  // fused flag kernel
      int p = atomicAdd(cnt, 1);
      list[p] = n;
      fixb[n] = 0xFFFFFFFFFFFFFFFFULL;
    }
  }
  __syncthreads();

  // ---- z_q gather: float4 codebook loads, coalesced stores over t ----
  {
    const int t = tid & 127, d0 = tid >> 7;         // d0 0..3
    const int kk = fin[t];
    const f32x4* row = (const f32x4*)(e + (size_t)kk * D_DIM) + d0 * 16;
    #pragma unroll 4
    for (int q = 0; q < 16; ++q) {
      f32x4 v = row[q];
      const int d = d0 * 64 + q * 4;
      out[(size_t)(d + 0) * N_TOK + n0 + t] = v[0];
      out[(size_t)(d + 1) * N_TOK + n0 + t] = v[1];
      out[(size_t)(d + 2) * N_TOK + n0 + t] = v[2];
      out[(size_t)(d + 3) * N_TOK + n0 + t] = v[3];
    }
  }
}

// ===========================================================================
// C2: exact fp32 rescan of flagged tokens, 1024-code slabs, packed atomicMin
// ===========================================================================
__global__ __launch_bounds__(256) void rescan_kernel(
    const float* __restrict__ z, const float* __restrict__ e,
    const float* __restrict__ esq, const int* __restrict__ cnt,
    const int* __restrict__ list, unsigned long long* __restrict__ fixb) {
  __shared__ float zs[256];
  __shared__ unsigned long long red[256];
  const int tid = threadIdx.x;
  const int items = (*(volatile const int*)cnt) * 8;
  for (int it = blockIdx.x; it < items; it += gridDim.x) {
    int n = list[it >> 3];
    int slab = (it & 7) * 1024;
    __syncthreads();
    zs[tid] = z[(size_t)tid * N_TOK + n];
    __syncthreads();
    unsigned long long lmin = 0xFFFFFFFFFFFFFFFFULL;
    for (int q = 0; q < 4; ++q) {
      int k = slab + q * 256 + tid;
      const f32x4* row = (const f32x4*)(e + (size_t)k * D_DIM);
      float dot = 0.f;
      #pragma unroll 8
      for (int d4 = 0; d4 < 64; ++d4) {
        f32x4 ev = row[d4];
        dot += zs[d4*4+0]*ev[0] + zs[d4*4+1]*ev[1] + zs[d4*4+2]*ev[2] + zs[d4*4+3]*ev[3];
      }
      float s = esq[k] - 2.0f * dot + 1024.0f;          // bias > 0 for packing
      unsigned long long p = ((unsigned long long)__float_as_uint(s) << 32) | (unsigned)k;
      lmin = (p < lmin) ? p : lmin;
    }
    red[tid] = lmin; __syncthreads();
    for (int off = 128; off > 0; off >>= 1) {
      if (tid < off && red[tid + off] < red[tid]) red[tid] = red[tid + off];
      __syncthreads();
    }
    if (tid == 0) atomicMin(&fixb[n], red[0]);
  }
}

// ===========================================================================
// C3: write exact idx + z_q column for flagged tokens
// ===========================================================================
__global__ __launch_bounds__(256) void fixup_kernel(const float* __restrict__ marg,
                                                    const unsigned long long* __restrict__ fixb,
                                                    const float* __restrict__ e,
                                                    float* __restrict__ out) {
  __shared__ int fk[64];
  const int tid = threadIdx.x;
  const int n0 = blockIdx.x * 64;
  if (tid < 64) {
    int n = n0 + tid;
    int k = -1;
    if (marg[n] < TAU) {
      k = (int)(unsigned)(fixb[n] & 0xFFFFFFFFu);
      out[(size_t)D_DIM * N_TOK + n] = (float)k;
    }
    fk[tid] = k;
  }
  __syncthreads();
  int t = tid & 63, d0 = tid >> 6;                // d0 0..3
  int k = fk[t];
  if (k >= 0) {
    const float* row = e + (size_t)k * D_DIM;
    for (int dd = 0; dd < 64; ++dd) {
      int d = d0 * 64 + dd;
      out[(size_t)d * N_TOK + n0 + t] = row[d];
    }
  }
}

// ======================= fallback (round-1 fp32 path) =======================
__global__ __launch_bounds__(256) void esq_kernel(const float* __restrict__ e,
                                                  float* __restrict__ esq) {
  const int wave = threadIdx.x >> 6, lane = threadIdx.x & 63;
  const int k = blockIdx.x * 4 + wave;
  const float4* row = (const float4*)(e + (size_t)k * D_DIM);
  float4 v = row[lane];
  float s = v.x*v.x + v.y*v.y + v.z*v.z + v.w*v.w;
  #pragma unroll
  for (int off = 32; off > 0; off >>= 1) s += __shfl_down(s, off, 64);
  if (lane == 0) esq[k] = s;
}

__global__ __launch_bounds__(256) void vq_kernel(const float* __restrict__ z,
                                                 const float* __restrict__ e,
                                                 const float* __restrict__ esq,
                                                 float* __restrict__ out) {
  __shared__ float zs[D_DIM][64];
  const int tid = threadIdx.x, tx = tid & 15, ty = tid >> 4;
  const int n0 = blockIdx.x * 64;
  {
    const int c = tid & 63, d0 = tid >> 6;
    #pragma unroll 4
    for (int d = d0; d < D_DIM; d += 4) zs[d][c] = z[(size_t)d * N_TOK + n0 + c];
  }
  __syncthreads();
  float bestv[4] = {3.4e38f,3.4e38f,3.4e38f,3.4e38f};
  int   besti[4] = {0,0,0,0};
  for (int k0 = 0; k0 < K_CB; k0 += 64) {
    const float4* er[4]; float eqv[4];
    #pragma unroll
    for (int j = 0; j < 4; ++j) {
      int k = k0 + ty + 16 * j;
      er[j] = (const float4*)(e + (size_t)k * D_DIM);
      eqv[j] = esq[k];
    }
    float acc[4][4];
    #pragma unroll
    for (int i = 0; i < 4; ++i)
      #pragma unroll
      for (int j = 0; j < 4; ++j) acc[i][j] = 0.f;
    #pragma unroll 4
    for (int d4 = 0; d4 < D_DIM/4; ++d4) {
      float4 ev[4];
      #pragma unroll
      for (int j = 0; j < 4; ++j) ev[j] = er[j][d4];
      #pragma unroll
      for (int dd = 0; dd < 4; ++dd) {
        float zv[4];
        #pragma unroll
        for (int i = 0; i < 4; ++i) zv[i] = zs[d4*4+dd][tx + 16*i];
        #pragma unroll
        for (int i = 0; i < 4; ++i)
          #pragma unroll
          for (int j = 0; j < 4; ++j) acc[i][j] += zv[i] * ((const float*)&ev[j])[dd];
      }
    }
    #pragma unroll
    for (int j = 0; j < 4; ++j) {
      int k = k0 + ty + 16 * j;
      #pragma unroll
      for (int i = 0; i < 4; ++i) {
        float s = eqv[j] - 2.0f * acc[i][j];
        if (s < bestv[i]) { bestv[i] = s; besti[i] = k; }
      }
    }
  }
  __syncthreads();
  float* lds = &zs[0][0];
  float* vred = lds; int* ired = (int*)lds + 1024; int* fin = (int*)lds + 2048;
  #pragma unroll
  for (int i = 0; i < 4; ++i) {
    int l = tx + 16 * i;
    vred[ty * 64 + l] = bestv[i]; ired[ty * 64 + l] = besti[i];
  }
  __syncthreads();
  if (tid < 64) {
    float bv = vred[tid]; int bi = ired[tid];
    #pragma unroll
    for (int t = 1; t < 16; ++t) {
      float v = vred[t*64+tid]; int ix = ired[t*64+tid];
      if (v < bv || (v == bv && ix < bi)) { bv = v; bi = ix; }
    }
    fin[tid] = bi;
    out[(size_t)D_DIM * N_TOK + n0 + tid] = (float)bi;
  }
  __syncthreads();
  {
    const int l = tid & 63, d0 = tid >> 6;
    const int kk = fin[l];
    const float* row = e + (size_t)kk * D_DIM;
    #pragma unroll 4
    for (int d = d0; d < D_DIM; d += 4) out[(size_t)d * N_TOK + n0 + l] = row[d];
  }
}

extern "C" void kernel_launch(void* const* d_in, const int* in_sizes, int n_in,
                              void* d_out, int out_size, void* d_ws, size_t ws_size,
                              hipStream_t stream) {
  const float* z = (const float*)d_in[0];
  const float* e = (const float*)d_in[1];
  float* out = (float*)d_out;
  char* ws = (char*)d_ws;

  if (ws_size >= WS_NEED) {
    float* esq = (float*)(ws + OFF_ESQ);
    int* cnt = (int*)(ws + OFF_CNT);
    float* marg = (float*)(ws + OFF_MARG);
    int* list = (int*)(ws + OFF_LIST);
    unsigned long long* fixb = (unsigned long long*)(ws + OFF_FIXB);
    short* eht = (short*)(ws + OFF_EHT);
    short* elt = (short*)(ws + OFF_ELT);

    (void)hipFuncSetAttribute((const void*)vq_main_kernel,
                              hipFuncAttributeMaxDynamicSharedMemorySize, SMEM_BYTES);

    eprep_kernel<<<1024, 256, 0, stream>>>(e, eht, elt, esq, cnt);
    vq_main_kernel<<<256, 512, SMEM_BYTES, stream>>>(z, e, esq, eht, elt,
                                                     out, marg, cnt, list, fixb);
    rescan_kernel<<<1024, 256, 0, stream>>>(z, e, esq, cnt, list, fixb);
    fixup_kernel<<<512, 256, 0, stream>>>(marg, fixb, e, out);
  } else {
    float* esq = (float*)(ws);
    esq_kernel<<<K_CB / 4, 256, 0, stream>>>(e, esq);
    vq_kernel<<<N_TOK / 64, 256, 0, stream>>>(z, e, esq, out);
  }
}

// Round 4
// 544.081 us; speedup vs baseline: 4.2903x; 1.6320x over previous
//
#include <hip/hip_runtime.h>

#define D_DIM 256
#define N_TOK 32768
#define K_CB  8192
#define TAU   0.05f

typedef float  f32x16 __attribute__((ext_vector_type(16)));
typedef float  f32x4  __attribute__((ext_vector_type(4)));
typedef short  s16x8  __attribute__((ext_vector_type(8)));

// ---- workspace layout (bytes) ----
#define OFF_ESQ   0                        // 8192 f32 (32 KB)
#define OFF_CNT   32768                    // int (+pad)
#define OFF_MARG  33024                    // 32768 f32 (128 KB)
#define OFF_LIST  164096                   // 32768 i32 (128 KB)
#define OFF_FIXB  295168                   // 32768 u64 (256 KB)
#define OFF_EHT   557312                   // 32*8192*8 bf16 = 4 MB
#define OFF_ELT   (OFF_EHT + 4194304)
#define OFF_ZG    (OFF_ELT + 4194304)      // 512 groups * 256 d * 64 tok f32 = 32 MB
#define MAXGRP    512
#define WS_NEED   ((size_t)(OFF_ZG + (size_t)MAXGRP * 16384 * 4))

#define SMEM_BYTES 163840                  // 64K zs_h + 64K zs_l + 32K esq

#define GLOAD_LDS16(g, s) \
  __builtin_amdgcn_global_load_lds((const __attribute__((address_space(1))) unsigned int*)(g), \
                                   (__attribute__((address_space(3))) unsigned int*)(s), 16, 0, 0)

static __device__ __forceinline__ short f32_to_bf16(float f) {
  unsigned u = __float_as_uint(f);
  unsigned r = (u + 0x7FFFu + ((u >> 16) & 1u)) >> 16;   // RNE
  return (short)r;
}
static __device__ __forceinline__ float bf16_to_f32(short s) {
  return __uint_as_float(((unsigned)(unsigned short)s) << 16);
}

// ===========================================================================
// P: eht/elt[c][k][8] = bf16 hi/lo split of e[k][8c+j]; esq[k]; zero counter
// ===========================================================================
__global__ __launch_bounds__(256) void eprep_kernel(const float* __restrict__ e,
                                                    short* __restrict__ eht,
                                                    short* __restrict__ elt,
                                                    float* __restrict__ esq,
                                                    int* __restrict__ cnt) {
  if (blockIdx.x == 0 && threadIdx.x == 0) *cnt = 0;
  const int tid = threadIdx.x;
  const int c = tid & 31, kk = tid >> 5;
  const int k = blockIdx.x * 8 + kk;
  float v[8]; float ss = 0.f;
  #pragma unroll
  for (int i = 0; i < 8; ++i) {
    v[i] = e[(size_t)k * D_DIM + c * 8 + i];
    ss += v[i] * v[i];
  }
  #pragma unroll
  for (int m = 1; m < 32; m <<= 1) ss += __shfl_xor(ss, m, 64);  // 32-lane group sum
  if (c == 0) esq[k] = ss;
  s16x8 hv, lv;
  #pragma unroll
  for (int i = 0; i < 8; ++i) {
    short h = f32_to_bf16(v[i]);
    short l = f32_to_bf16(v[i] - bf16_to_f32(h));
    hv[i] = h; lv[i] = l;
  }
  *(s16x8*)(eht + ((size_t)c * K_CB + k) * 8) = hv;
  *(s16x8*)(elt + ((size_t)c * K_CB + k) * 8) = lv;
}

// ===========================================================================
// Main: 256 blocks x 512 thr (8 waves). 128 tokens/block in LDS (hi/lo bf16,
// split in-register at block start). e-fragments stream GLOBAL->VGPR. Zero
// barriers in the K-loop. Wave (th=w>>2, cg=w&3): 128 codes x 64 tokens via
// 4x2 frags of mfma_f32_32x32x16_bf16, 3-term bf16-split (hh+hl+lh).
// score = esq[k] + dot(-2z, e). Tracks best+second; margin<TAU -> rescan list.
// ===========================================================================
__global__ __launch_bounds__(512, 2) void vq_main_kernel(
    const float* __restrict__ z, const float* __restrict__ e,
    const float* __restrict__ esq_g,
    const short* __restrict__ eht, const short* __restrict__ elt,
    float* __restrict__ out, float* __restrict__ marg,
    int* __restrict__ cnt, int* __restrict__ list,
    unsigned long long* __restrict__ fixb) {
  extern __shared__ char smem[];
  short* zs_h = (short*)(smem);                 // [32][128][8] = 64 KB
  short* zs_l = (short*)(smem + 65536);         // 64 KB
  float* eqs  = (float*)(smem + 131072);        // [8192] f32 = 32 KB

  const int tid  = threadIdx.x;
  const int w    = tid >> 6;
  const int lane = tid & 63;
  const int half = lane >> 5;
  const int l31  = lane & 31;
  const int th   = w >> 2;            // token half (0/1)
  const int cg   = w & 3;             // code subgroup
  const int n0   = blockIdx.x * 128;

  // ---- stage all esq once: 32 KB, 4 insts/wave ----
  #pragma unroll
  for (int i = 0; i < 4; ++i) {
    int idx = (w * 4 + i) * 256;
    GLOAD_LDS16(esq_g + idx + lane * 4, eqs + idx);
  }

  // ---- split -2*z into bf16 hi/lo directly into LDS (fused zprep) ----
  {
    const int t = tid & 127;
    const int cb = (tid >> 7) * 8;    // 0,8,16,24
    #pragma unroll
    for (int cc = 0; cc < 8; ++cc) {
      const int c = cb + cc;
      s16x8 hv, lv;
      #pragma unroll
      for (int i = 0; i < 8; ++i) {
        float x = -2.0f * z[(size_t)(c * 8 + i) * N_TOK + n0 + t];  // coalesced over t
        short h = f32_to_bf16(x);
        short l = f32_to_bf16(x - bf16_to_f32(h));
        hv[i] = h; lv[i] = l;
      }
      *(s16x8*)(zs_h + ((size_t)c * 128 + t) * 8) = hv;
      *(s16x8*)(zs_l + ((size_t)c * 128 + t) * 8) = lv;
    }
  }
  __syncthreads();   // the only barrier before the merge

  float bestv[2] = {3.4e38f, 3.4e38f};
  float secv[2]  = {3.4e38f, 3.4e38f};
  int   bestk[2] = {0, 0};

  for (int k0 = 0; k0 < K_CB; k0 += 512) {
    const int kb = k0 + cg * 128;
    f32x16 acc[4][2];
    #pragma unroll
    for (int f = 0; f < 4; ++f)
      #pragma unroll
      for (int j = 0; j < 2; ++j)
        #pragma unroll
        for (int r = 0; r < 16; ++r) acc[f][j][r] = 0.f;

    #pragma unroll 4
    for (int dc = 0; dc < 16; ++dc) {
      s16x8 ah[4], al[4], bh[2], bl[2];
      const size_t ebase = ((size_t)(2 * dc + half) * K_CB + kb + l31) * 8;
      #pragma unroll
      for (int f = 0; f < 4; ++f) {
        ah[f] = *(const s16x8*)(eht + ebase + f * 32 * 8);   // global, coalesced 16B/lane
        al[f] = *(const s16x8*)(elt + ebase + f * 32 * 8);
      }
      const int zbase = ((2 * dc + half) * 128 + th * 64 + l31) * 8;
      #pragma unroll
      for (int j = 0; j < 2; ++j) {
        bh[j] = *(const s16x8*)(zs_h + zbase + j * 32 * 8);
        bl[j] = *(const s16x8*)(zs_l + zbase + j * 32 * 8);
      }
      #pragma unroll
      for (int f = 0; f < 4; ++f)
        #pragma unroll
        for (int j = 0; j < 2; ++j) {
          acc[f][j] = __builtin_amdgcn_mfma_f32_32x32x16_bf16(ah[f], bh[j], acc[f][j], 0, 0, 0);
          acc[f][j] = __builtin_amdgcn_mfma_f32_32x32x16_bf16(ah[f], bl[j], acc[f][j], 0, 0, 0);
          acc[f][j] = __builtin_amdgcn_mfma_f32_32x32x16_bf16(al[f], bh[j], acc[f][j], 0, 0, 0);
        }
    }

    // epilogue: score = acc + esq; running best/second (k ascending per lane)
    #pragma unroll
    for (int f = 0; f < 4; ++f) {
      const int base = kb + 32 * f + 4 * half;
      #pragma unroll
      for (int g = 0; g < 4; ++g) {
        f32x4 eqv = *(const f32x4*)(eqs + base + 8 * g);    // broadcast read
        #pragma unroll
        for (int r = 0; r < 4; ++r) {
          const int reg = g * 4 + r;
          const int kglob = base + 8 * g + r;
          #pragma unroll
          for (int j = 0; j < 2; ++j) {
            float s = acc[f][j][reg] + eqv[r];
            if (s < bestv[j]) { secv[j] = bestv[j]; bestv[j] = s; bestk[j] = kglob; }
            else if (s < secv[j]) secv[j] = s;
          }
        }
      }
    }
  }

  // ---- cross-wave merge: 8 partials per token ----
  __syncthreads();
  float* pv  = (float*)(smem);                  // [8][128]
  int*   pk  = (int*)  (smem + 4096);
  float* ps  = (float*)(smem + 8192);
  int*   fin = (int*)  (smem + 12288);          // [128]
  const int slot = cg * 2 + half;
  #pragma unroll
  for (int j = 0; j < 2; ++j) {
    const int t = th * 64 + 32 * j + l31;
    pv[slot * 128 + t] = bestv[j];
    pk[slot * 128 + t] = bestk[j];
    ps[slot * 128 + t] = secv[j];
  }
  __syncthreads();
  if (tid < 128) {
    const int t = tid;
    float bv = pv[t]; int bk = pk[t]; float sc = ps[t];
    #pragma unroll
    for (int s2 = 1; s2 < 8; ++s2) {
      float v = pv[s2 * 128 + t]; int k2 = pk[s2 * 128 + t]; float s3 = ps[s2 * 128 + t];
      if (v < bv || (v == bv && k2 < bk)) { sc = fminf(bv, s3); bv = v; bk = k2; }
      else                                { sc = fminf(sc, v); }
    }
    fin[t] = bk;
    const int n = n0 + t;
    out[(size_t)D_DIM * N_TOK + n] = (float)bk;     // indices as float (exact)
    const float m = sc - bv;
    marg[n] = m;
    if (m < TAU) {                                  // fused flag kernel
      int p = atomicAdd(cnt, 1);
      list[p] = n;
      fixb[n] = 0xFFFFFFFFFFFFFFFFULL;
    }
  }
  __syncthreads();

  // ---- z_q gather: float4 codebook loads, coalesced stores over t ----
  {
    const int t = tid & 127, d0 = tid >> 7;         // d0 0..3
    const int kk = fin[t];
    const f32x4* row = (const f32x4*)(e + (size_t)kk * D_DIM) + d0 * 16;
    #pragma unroll 4
    for (int q = 0; q < 16; ++q) {
      f32x4 v = row[q];
      const int d = d0 * 64 + q * 4;
      out[(size_t)(d + 0) * N_TOK + n0 + t] = v[0];
      out[(size_t)(d + 1) * N_TOK + n0 + t] = v[1];
      out[(size_t)(d + 2) * N_TOK + n0 + t] = v[2];
      out[(size_t)(d + 3) * N_TOK + n0 + t] = v[3];
    }
  }
}

// ===========================================================================
// G: gather flagged z-columns into contiguous zg[group][d][64] tiles.
// Padding lanes clamp to list[cnt-1] (duplicate work, idempotent merge).
// ===========================================================================
__global__ __launch_bounds__(256) void gather_kernel(const float* __restrict__ z,
                                                     const int* __restrict__ cnt,
                                                     const int* __restrict__ list,
                                                     float* __restrict__ zg) {
  const int c = *(volatile const int*)cnt;
  if (c == 0) return;
  int groups = (c + 63) >> 6;
  if (groups > MAXGRP) groups = MAXGRP;
  const int i  = threadIdx.x & 63;
  const int dq = threadIdx.x >> 6;               // 0..3
  for (int g = blockIdx.x; g < groups; g += gridDim.x) {
    int idx = g * 64 + i;
    int n = list[idx < c ? idx : c - 1];
    #pragma unroll 4
    for (int dd = 0; dd < 64; ++dd) {
      int d = dq * 64 + dd;
      zg[(size_t)g * 16384 + d * 64 + i] = z[(size_t)d * N_TOK + n];  // stores coalesced over i
    }
  }
}

// ===========================================================================
// C2: batched exact fp32 rescan. Persistent grid over items =
// (64-token group) x (256-code slab). Round-1 register-tiled structure
// (53 TF-class): thread (tx,ty) covers tokens {tx+16i} x codes {ty+16j}.
// Merge via packed (f32bits<<32|k) u64 atomicMin (lowest k on ties).
// ===========================================================================
__global__ __launch_bounds__(256) void rescan_kernel(
    const float* __restrict__ zg, const float* __restrict__ e,
    const float* __restrict__ esq, const int* __restrict__ cnt,
    const int* __restrict__ list, unsigned long long* __restrict__ fixb) {
  __shared__ float zs[D_DIM * 64];                 // 64 KB, zs[d*64 + t]
  __shared__ unsigned long long red[16 * 64];      // 8 KB
  const int tid = threadIdx.x;
  const int c = *(volatile const int*)cnt;
  if (c == 0) return;
  int groups = (c + 63) >> 6;
  if (groups > MAXGRP) groups = MAXGRP;
  const int items = groups * 32;                   // 32 slabs of 256 codes
  const int tx = tid & 15, ty = tid >> 4;

  for (int it = blockIdx.x; it < items; it += gridDim.x) {
    const int g = it >> 5;
    const int slab = (it & 31) * 256;
    __syncthreads();                               // protect zs/red reuse
    #pragma unroll 8
    for (int q = 0; q < 64; ++q)
      zs[q * 256 + tid] = zg[(size_t)g * 16384 + q * 256 + tid];  // coalesced
    __syncthreads();

    unsigned long long lmin[4] = {~0ULL, ~0ULL, ~0ULL, ~0ULL};
    for (int k0 = 0; k0 < 256; k0 += 64) {
      const f32x4* er[4]; float eqv[4];
      #pragma unroll
      for (int j = 0; j < 4; ++j) {
        int k = slab + k0 + ty + 16 * j;
        er[j] = (const f32x4*)(e + (size_t)k * D_DIM);
        eqv[j] = esq[k];
      }
      float acc[4][4];
      #pragma unroll
      for (int i = 0; i < 4; ++i)
        #pragma unroll
        for (int j = 0; j < 4; ++j) acc[i][j] = 0.f;
      #pragma unroll 4
      for (int d4 = 0; d4 < D_DIM / 4; ++d4) {
        f32x4 ev[4];
        #pragma unroll
        for (int j = 0; j < 4; ++j) ev[j] = er[j][d4];
        #pragma unroll
        for (int dd = 0; dd < 4; ++dd) {
          float zv[4];
          #pragma unroll
          for (int i = 0; i < 4; ++i) zv[i] = zs[(d4 * 4 + dd) * 64 + tx + 16 * i];
          #pragma unroll
          for (int i = 0; i < 4; ++i)
            #pragma unroll
            for (int j = 0; j < 4; ++j) acc[i][j] += zv[i] * ev[j][dd];
        }
      }
      #pragma unroll
      for (int j = 0; j < 4; ++j) {
        const int k = slab + k0 + ty + 16 * j;
        #pragma unroll
        for (int i = 0; i < 4; ++i) {
          float s = eqv[j] - 2.0f * acc[i][j] + 1024.0f;   // bias > 0 for packing
          unsigned long long p =
              ((unsigned long long)__float_as_uint(s) << 32) | (unsigned)k;
          lmin[i] = (p < lmin[i]) ? p : lmin[i];
        }
      }
    }
    #pragma unroll
    for (int i = 0; i < 4; ++i) red[ty * 64 + tx + 16 * i] = lmin[i];
    __syncthreads();
    if (tid < 64) {
      unsigned long long m = red[tid];
      #pragma unroll
      for (int t = 1; t < 16; ++t) {
        unsigned long long v = red[t * 64 + tid];
        m = (v < m) ? v : m;
      }
      int idx = g * 64 + tid;
      int n = list[idx < c ? idx : c - 1];
      atomicMin(&fixb[n], m);
    }
  }
}

// ===========================================================================
// C3: write exact idx + z_q column for flagged tokens
// ===========================================================================
__global__ __launch_bounds__(256) void fixup_kernel(const float* __restrict__ marg,
                                                    const unsigned long long* __restrict__ fixb,
                                                    const float* __restrict__ e,
                                                    float* __restrict__ out) {
  __shared__ int fk[64];
  const int tid = threadIdx.x;
  const int n0 = blockIdx.x * 64;
  if (tid < 64) {
    int n = n0 + tid;
    int k = -1;
    if (marg[n] < TAU) {
      k = (int)(unsigned)(fixb[n] & 0xFFFFFFFFu);
      out[(size_t)D_DIM * N_TOK + n] = (float)k;
    }
    fk[tid] = k;
  }
  __syncthreads();
  int t = tid & 63, d0 = tid >> 6;                // d0 0..3
  int k = fk[t];
  if (k >= 0) {
    const float* row = e + (size_t)k * D_DIM;
    for (int dd = 0; dd < 64; ++dd) {
      int d = d0 * 64 + dd;
      out[(size_t)d * N_TOK + n0 + t] = row[d];
    }
  }
}

// ======================= fallback (round-1 fp32 path) =======================
__global__ __launch_bounds__(256) void esq_kernel(const float* __restrict__ e,
                                                  float* __restrict__ esq) {
  const int wave = threadIdx.x >> 6, lane = threadIdx.x & 63;
  const int k = blockIdx.x * 4 + wave;
  const float4* row = (const float4*)(e + (size_t)k * D_DIM);
  float4 v = row[lane];
  float s = v.x*v.x + v.y*v.y + v.z*v.z + v.w*v.w;
  #pragma unroll
  for (int off = 32; off > 0; off >>= 1) s += __shfl_down(s, off, 64);
  if (lane == 0) esq[k] = s;
}

__global__ __launch_bounds__(256) void vq_kernel(const float* __restrict__ z,
                                                 const float* __restrict__ e,
                                                 const float* __restrict__ esq,
                                                 float* __restrict__ out) {
  __shared__ float zs[D_DIM][64];
  const int tid = threadIdx.x, tx = tid & 15, ty = tid >> 4;
  const int n0 = blockIdx.x * 64;
  {
    const int c = tid & 63, d0 = tid >> 6;
    #pragma unroll 4
    for (int d = d0; d < D_DIM; d += 4) zs[d][c] = z[(size_t)d * N_TOK + n0 + c];
  }
  __syncthreads();
  float bestv[4] = {3.4e38f,3.4e38f,3.4e38f,3.4e38f};
  int   besti[4] = {0,0,0,0};
  for (int k0 = 0; k0 < K_CB; k0 += 64) {
    const float4* er[4]; float eqv[4];
    #pragma unroll
    for (int j = 0; j < 4; ++j) {
      int k = k0 + ty + 16 * j;
      er[j] = (const float4*)(e + (size_t)k * D_DIM);
      eqv[j] = esq[k];
    }
    float acc[4][4];
    #pragma unroll
    for (int i = 0; i < 4; ++i)
      #pragma unroll
      for (int j = 0; j < 4; ++j) acc[i][j] = 0.f;
    #pragma unroll 4
    for (int d4 = 0; d4 < D_DIM/4; ++d4) {
      float4 ev[4];
      #pragma unroll
      for (int j = 0; j < 4; ++j) ev[j] = er[j][d4];
      #pragma unroll
      for (int dd = 0; dd < 4; ++dd) {
        float zv[4];
        #pragma unroll
        for (int i = 0; i < 4; ++i) zv[i] = zs[d4*4+dd][tx + 16*i];
        #pragma unroll
        for (int i = 0; i < 4; ++i)
          #pragma unroll
          for (int j = 0; j < 4; ++j) acc[i][j] += zv[i] * ((const float*)&ev[j])[dd];
      }
    }
    #pragma unroll
    for (int j = 0; j < 4; ++j) {
      int k = k0 + ty + 16 * j;
      #pragma unroll
      for (int i = 0; i < 4; ++i) {
        float s = eqv[j] - 2.0f * acc[i][j];
        if (s < bestv[i]) { bestv[i] = s; besti[i] = k; }
      }
    }
  }
  __syncthreads();
  float* lds = &zs[0][0];
  float* vred = lds; int* ired = (int*)lds + 1024; int* fin = (int*)lds + 2048;
  #pragma unroll
  for (int i = 0; i < 4; ++i) {
    int l = tx + 16 * i;
    vred[ty * 64 + l] = bestv[i]; ired[ty * 64 + l] = besti[i];
  }
  __syncthreads();
  if (tid < 64) {
    float bv = vred[tid]; int bi = ired[tid];
    #pragma unroll
    for (int t = 1; t < 16; ++t) {
      float v = vred[t*64+tid]; int ix = ired[t*64+tid];
      if (v < bv || (v == bv && ix < bi)) { bv = v; bi = ix; }
    }
    fin[tid] = bi;
    out[(size_t)D_DIM * N_TOK + n0 + tid] = (float)bi;
  }
  __syncthreads();
  {
    const int l = tid & 63, d0 = tid >> 6;
    const int kk = fin[l];
    const float* row = e + (size_t)kk * D_DIM;
    #pragma unroll 4
    for (int d = d0; d < D_DIM; d += 4) out[(size_t)d * N_TOK + n0 + l] = row[d];
  }
}

extern "C" void kernel_launch(void* const* d_in, const int* in_sizes, int n_in,
                              void* d_out, int out_size, void* d_ws, size_t ws_size,
                              hipStream_t stream) {
  const float* z = (const float*)d_in[0];
  const float* e = (const float*)d_in[1];
  float* out = (float*)d_out;
  char* ws = (char*)d_ws;

  if (ws_size >= WS_NEED) {
    float* esq = (float*)(ws + OFF_ESQ);
    int* cnt = (int*)(ws + OFF_CNT);
    float* marg = (float*)(ws + OFF_MARG);
    int* list = (int*)(ws + OFF_LIST);
    unsigned long long* fixb = (unsigned long long*)(ws + OFF_FIXB);
    short* eht = (short*)(ws + OFF_EHT);
    short* elt = (short*)(ws + OFF_ELT);
    float* zg  = (float*)(ws + OFF_ZG);

    (void)hipFuncSetAttribute((const void*)vq_main_kernel,
                              hipFuncAttributeMaxDynamicSharedMemorySize, SMEM_BYTES);

    eprep_kernel<<<1024, 256, 0, stream>>>(e, eht, elt, esq, cnt);
    vq_main_kernel<<<256, 512, SMEM_BYTES, stream>>>(z, e, esq, eht, elt,
                                                     out, marg, cnt, list, fixb);
    gather_kernel<<<64, 256, 0, stream>>>(z, cnt, list, zg);
    rescan_kernel<<<256, 256, 0, stream>>>(zg, e, esq, cnt, list, fixb);
    fixup_kernel<<<512, 256, 0, stream>>>(marg, fixb, e, out);
  } else {
    float* esq = (float*)(ws);
    esq_kernel<<<K_CB / 4, 256, 0, stream>>>(e, esq);
    vq_kernel<<<N_TOK / 64, 256, 0, stream>>>(z, e, esq, out);
  }
}